// Round 10
// baseline (288.731 us; speedup 1.0000x reference)
//
#include <hip/hip_runtime.h>
#include <hip/hip_bf16.h>
#include <float.h>
#include <stdint.h>

typedef __bf16 bf16x8 __attribute__((ext_vector_type(8)));
typedef __bf16 bf16x4 __attribute__((ext_vector_type(4)));
typedef float  f32x4  __attribute__((ext_vector_type(4)));

#define T_SEQ 4096
#define DMODEL 512
#define NH 8
#define HDIM 64
#define KS1 4                       // k-splits in stats pass
#define L2E 1.44269504088896340736f

__device__ __forceinline__ float fexp2(float x) { return __builtin_amdgcn_exp2f(x); }

// async global->LDS, 16B per lane.  LDS dest is wave-uniform base + lane*16;
// global source is per-lane (pre-swizzled so linear LDS slots get swizzled data).
__device__ __forceinline__ void gl_lds16(const __bf16* g, char* l) {
    __builtin_amdgcn_global_load_lds(
        (const __attribute__((address_space(1))) unsigned int*)(g),
        (__attribute__((address_space(3))) unsigned int*)(l),
        16, 0, 0);
}

// ---------------------------------------------------------------------------
// Kernel 1: fused QKV projection.  q scaled by 1/8; V written TRANSPOSED
// (vt[feature][seq]) for fragment loads in the attention pass.
// ---------------------------------------------------------------------------
__global__ __launch_bounds__(256) void qkv_kernel(
    const float* __restrict__ qin, const float* __restrict__ kin, const float* __restrict__ vin,
    const float* __restrict__ Wq, const float* __restrict__ bq,
    const float* __restrict__ Wk, const float* __restrict__ bk,
    const float* __restrict__ Wv, const float* __restrict__ bv,
    __bf16* __restrict__ qo, __bf16* __restrict__ ko, __bf16* __restrict__ vt)
{
    __shared__ char lds[16384];
    char* Ab = lds;
    char* Bb = lds + 8192;

    const int z = blockIdx.z;
    const float* X    = (z == 0) ? qin : (z == 1) ? kin : vin;
    const float* W    = (z == 0) ? Wq  : (z == 1) ? Wk  : Wv;
    const float* bias = (z == 0) ? bq  : (z == 1) ? bk  : bv;

    const int m0 = blockIdx.x * 64;
    const int n0 = blockIdx.y * 64;
    const int tid  = threadIdx.x;
    const int w    = tid >> 6;
    const int lane = tid & 63;
    const int lrow = lane & 15;
    const int lgrp = lane >> 4;

    f32x4 acc[4] = {};
    const int r  = tid >> 2;
    const int c0 = (tid & 3) * 16;

    for (int kt = 0; kt < 8; ++kt) {
        const int k0 = kt * 64;
        const float* gA = X + (size_t)(m0 + r) * DMODEL + k0 + c0;
        const float* gB = W + (size_t)(n0 + r) * DMODEL + k0 + c0;
        const int sw = (r & 7) << 4;
#pragma unroll
        for (int i = 0; i < 4; ++i) {
            float4 a4 = *(const float4*)(gA + 4 * i);
            float4 b4 = *(const float4*)(gB + 4 * i);
            bf16x4 av, bv4;
            av[0] = (__bf16)a4.x; av[1] = (__bf16)a4.y; av[2] = (__bf16)a4.z; av[3] = (__bf16)a4.w;
            bv4[0] = (__bf16)b4.x; bv4[1] = (__bf16)b4.y; bv4[2] = (__bf16)b4.z; bv4[3] = (__bf16)b4.w;
            *(bf16x4*)(Ab + r * 128 + ((c0 * 2 + 8 * i) ^ sw)) = av;
            *(bf16x4*)(Bb + r * 128 + ((c0 * 2 + 8 * i) ^ sw)) = bv4;
        }
        __syncthreads();
#pragma unroll
        for (int ks = 0; ks < 2; ++ks) {
            bf16x8 af = *(const bf16x8*)(Ab + (w * 16 + lrow) * 128 +
                                         ((ks * 64 + lgrp * 16) ^ ((lrow & 7) << 4)));
#pragma unroll
            for (int ns = 0; ns < 4; ++ns) {
                bf16x8 bf = *(const bf16x8*)(Bb + (ns * 16 + lrow) * 128 +
                                             ((ks * 64 + lgrp * 16) ^ ((lrow & 7) << 4)));
                acc[ns] = __builtin_amdgcn_mfma_f32_16x16x32_bf16(af, bf, acc[ns], 0, 0, 0);
            }
        }
        __syncthreads();
    }

    if (z == 2) {
        // transpose epilogue via LDS: LT[col][row], granule swizzle on col
        char* LT = lds;
#pragma unroll
        for (int ns = 0; ns < 4; ++ns) {
            float bcol = bias[n0 + ns * 16 + lrow];
#pragma unroll
            for (int rr = 0; rr < 4; ++rr) {
                int col = ns * 16 + lrow;
                int row = w * 16 + lgrp * 4 + rr;
                *(__bf16*)(LT + col * 128 + ((row * 2) ^ ((col & 7) << 4))) =
                    (__bf16)(acc[ns][rr] + bcol);
            }
        }
        __syncthreads();
        int d  = tid >> 2;
        int nb = (tid & 3) * 32;
        bf16x8 t0 = *(const bf16x8*)(LT + d * 128 + (nb ^ ((d & 7) << 4)));
        bf16x8 t1 = *(const bf16x8*)(LT + d * 128 + ((nb + 16) ^ ((d & 7) << 4)));
        __bf16* dst = vt + (size_t)(n0 + d) * T_SEQ + m0 + (tid & 3) * 16;
        *(bf16x8*)dst = t0;
        *(bf16x8*)(dst + 8) = t1;
    } else {
        __bf16* out = (z == 0) ? qo : ko;
        const float sc = (z == 0) ? 0.125f : 1.0f;   // fold 1/sqrt(HD) into Q (exact)
#pragma unroll
        for (int ns = 0; ns < 4; ++ns) {
            float bcol = bias[n0 + ns * 16 + lrow];
#pragma unroll
            for (int rr = 0; rr < 4; ++rr) {
                int orow = m0 + w * 16 + lgrp * 4 + rr;
                out[(size_t)orow * DMODEL + n0 + ns * 16 + lrow] =
                    (__bf16)((acc[ns][rr] + bcol) * sc);
            }
        }
    }
}

// ---------------------------------------------------------------------------
// Kernel 2: softmax denominators, QBLK=128 (proven R9).  WG = 128 q-rows;
// each wave owns 32 (2x16 subtiles).  K staged in LDS dbuf, shared by 4 waves.
// ---------------------------------------------------------------------------
__global__ __launch_bounds__(256) void attn_stats(
    const __bf16* __restrict__ qb, const __bf16* __restrict__ kb,
    const int* __restrict__ mask, float* __restrict__ l_part)
{
    __shared__ char lds[16384];
    char* KB0 = lds;
    char* KB1 = lds + 8192;

    const int nwg  = 32 * NH * KS1;                     // 1024
    const int b    = blockIdx.x;
    const int rmap = (b & 7) * (nwg >> 3) + (b >> 3);   // XCD-chunked
    const int qsi  = rmap & 31;
    const int h    = (rmap >> 5) & (NH - 1);
    const int ksp  = rmap >> 8;
    const int q0   = qsi * 128;
    const int k0   = ksp * (T_SEQ / KS1);

    const int tid  = threadIdx.x;
    const int w    = tid >> 6;
    const int lane = tid & 63;
    const int lrow = lane & 15;
    const int lgrp = lane >> 4;
    const int swl  = (lrow & 7) << 4;
    const int q0w  = q0 + w * 32;

    bf16x8 qa[2][2];
#pragma unroll
    for (int q2 = 0; q2 < 2; ++q2) {
        const __bf16* qp = qb + (size_t)(q0w + q2 * 16 + lrow) * DMODEL + h * HDIM;
        qa[q2][0] = *(const bf16x8*)(qp + lgrp * 8);
        qa[q2][1] = *(const bf16x8*)(qp + 32 + lgrp * 8);
    }

    // staging source (pre-swizzled): lane slot -> (key, granule)
    const int key0 = w * 16 + (lane >> 3);
    const int key1 = key0 + 8;
    const int g    = lane & 7;
    const __bf16* sK0 = kb + (size_t)(k0 + key0) * DMODEL + h * HDIM + (g ^ (key0 & 7)) * 8;
    const __bf16* sK1 = kb + (size_t)(k0 + key1) * DMODEL + h * HDIM + (g ^ (key1 & 7)) * 8;

    float lsum[2][4] = {};

    gl_lds16(sK0, KB0 + w * 2048);
    gl_lds16(sK1, KB0 + w * 2048 + 1024);
    __syncthreads();

    char* cur = KB0;
    char* nxt = KB1;
    const int NT = (T_SEQ / KS1) / 64;   // 16
    for (int kt = 0; kt < NT; ++kt) {
        if (kt + 1 < NT) {
            gl_lds16(sK0 + (size_t)(kt + 1) * 64 * DMODEL, nxt + w * 2048);
            gl_lds16(sK1 + (size_t)(kt + 1) * 64 * DMODEL, nxt + w * 2048 + 1024);
        }

        f32x4 acc[2][4] = {};
        __builtin_amdgcn_s_setprio(1);
#pragma unroll
        for (int ns = 0; ns < 4; ++ns) {
            bf16x8 kf0 = *(const bf16x8*)(cur + (ns * 16 + lrow) * 128 + ((lgrp * 16) ^ swl));
            bf16x8 kf1 = *(const bf16x8*)(cur + (ns * 16 + lrow) * 128 + ((64 + lgrp * 16) ^ swl));
            acc[0][ns] = __builtin_amdgcn_mfma_f32_16x16x32_bf16(kf0, qa[0][0], acc[0][ns], 0, 0, 0);
            acc[0][ns] = __builtin_amdgcn_mfma_f32_16x16x32_bf16(kf1, qa[0][1], acc[0][ns], 0, 0, 0);
            acc[1][ns] = __builtin_amdgcn_mfma_f32_16x16x32_bf16(kf0, qa[1][0], acc[1][ns], 0, 0, 0);
            acc[1][ns] = __builtin_amdgcn_mfma_f32_16x16x32_bf16(kf1, qa[1][1], acc[1][ns], 0, 0, 0);
        }
        __builtin_amdgcn_s_setprio(0);

#pragma unroll
        for (int ns = 0; ns < 4; ++ns) {
            int4 mi = *(const int4*)(mask + k0 + kt * 64 + ns * 16 + lgrp * 4);
            f32x4 mb;
            mb[0] = mi.x ? -1e30f : 0.f;
            mb[1] = mi.y ? -1e30f : 0.f;
            mb[2] = mi.z ? -1e30f : 0.f;
            mb[3] = mi.w ? -1e30f : 0.f;
#pragma unroll
            for (int q2 = 0; q2 < 2; ++q2)
#pragma unroll
                for (int rr = 0; rr < 4; ++rr)
                    lsum[q2][ns] += fexp2(fmaf(acc[q2][ns][rr], L2E, mb[rr]));
        }
        __syncthreads();
        char* t = cur; cur = nxt; nxt = t;
    }

#pragma unroll
    for (int q2 = 0; q2 < 2; ++q2) {
        float tot = (lsum[q2][0] + lsum[q2][1]) + (lsum[q2][2] + lsum[q2][3]);
        tot += __shfl_xor(tot, 16);
        tot += __shfl_xor(tot, 32);
        if (lgrp == 0)
            l_part[((size_t)h * KS1 + ksp) * T_SEQ + q0w + q2 * 16 + lrow] = tot;
    }
}

// ---------------------------------------------------------------------------
// Kernel 3: main attention pass.  K staged in LDS dbuf (gl_lds16); V read
// DIRECTLY from L1/L2 as register fragments (identical across the 4 waves ->
// cache-served), prefetched with slack: ks=0 frags at tile top, ks=1 after
// QK^T.  LDS = K dbuf 16KB + P 8KB = 24KB -> 6 WG/CU.
// ---------------------------------------------------------------------------
__global__ __launch_bounds__(256) void attn_main(
    const __bf16* __restrict__ qb, const __bf16* __restrict__ kb,
    const __bf16* __restrict__ vt, const int* __restrict__ mask,
    const float* __restrict__ l_part,
    float* __restrict__ attn_out, void* __restrict__ opart,
    int KSP2, int of32)
{
    __shared__ char lds[24576];
    char* PB  = lds + 16384;   // 4 waves x 2 KB

    const int nwg  = 64 * NH * KSP2;
    const int b    = blockIdx.x;
    const int rmap = (b & 7) * (nwg >> 3) + (b >> 3);   // XCD-chunked (nwg%8==0)
    const int qbi  = rmap & 63;
    const int h    = (rmap >> 6) & (NH - 1);
    const int kz   = rmap >> 9;
    const int q0   = qbi * 64;
    const int kspan = T_SEQ / KSP2;
    const int k0   = kz * kspan;
    const int NT   = kspan / 64;

    const int tid  = threadIdx.x;
    const int w    = tid >> 6;
    const int lane = tid & 63;
    const int lrow = lane & 15;
    const int lgrp = lane >> 4;
    const int swl  = (lrow & 7) << 4;

    bf16x8 qa[2];
    {
        const __bf16* qp = qb + (size_t)(q0 + w * 16 + lrow) * DMODEL + h * HDIM;
        qa[0] = *(const bf16x8*)(qp + lgrp * 8);
        qa[1] = *(const bf16x8*)(qp + 32 + lgrp * 8);
    }

    float rl;
    {
        float s = 0.f;
#pragma unroll
        for (int ks = 0; ks < KS1; ++ks)
            s += l_part[((size_t)h * KS1 + ks) * T_SEQ + q0 + w * 16 + lrow];
        rl = 1.0f / s;
    }

    // K staging sources (pre-swizzled)
    const int key0 = w * 16 + (lane >> 3);
    const int key1 = key0 + 8;
    const int g    = lane & 7;
    const __bf16* sK0 = kb + (size_t)(k0 + key0) * DMODEL + h * HDIM + (g ^ (key0 & 7)) * 8;
    const __bf16* sK1 = kb + (size_t)(k0 + key1) * DMODEL + h * HDIM + (g ^ (key1 & 7)) * 8;

    // V fragment base: lane (lrow,lgrp) -> row d=lrow (+dsb*16), col k0 + lgrp*8
    const __bf16* vbase = vt + (size_t)(h * HDIM + lrow) * T_SEQ + k0 + lgrp * 8;

#define STAGE(tt, buf) do {                                             \
        size_t koff_ = (size_t)(tt) * 64 * DMODEL;                      \
        gl_lds16(sK0 + koff_, (buf) + w * 2048);                        \
        gl_lds16(sK1 + koff_, (buf) + w * 2048 + 1024);                 \
    } while (0)

    f32x4 oacc[4] = {};
    float* arow = attn_out + (size_t)h * T_SEQ * T_SEQ +
                  (size_t)(q0 + w * 16 + lrow) * T_SEQ + k0 + lgrp * 4;
    char* Pw = PB + w * 2048;

    char* bA = lds;
    char* bB = lds + 8192;

    STAGE(0, bA);
    __syncthreads();

    for (int kt = 0; kt < NT; ++kt) {
        if (kt + 1 < NT) STAGE(kt + 1, bB);

        // V prefetch, ks=0 half (used ~600 cycles later)
        const __bf16* vpt = vbase + (size_t)kt * 64;
        bf16x8 vf0[4];
#pragma unroll
        for (int dsb = 0; dsb < 4; ++dsb)
            vf0[dsb] = *(const bf16x8*)(vpt + (size_t)(dsb * 16) * T_SEQ);

        f32x4 acc[4] = {};
        __builtin_amdgcn_s_setprio(1);
#pragma unroll
        for (int ns = 0; ns < 4; ++ns) {
            bf16x8 kf0 = *(const bf16x8*)(bA + (ns * 16 + lrow) * 128 + ((lgrp * 16) ^ swl));
            bf16x8 kf1 = *(const bf16x8*)(bA + (ns * 16 + lrow) * 128 + ((64 + lgrp * 16) ^ swl));
            acc[ns] = __builtin_amdgcn_mfma_f32_16x16x32_bf16(kf0, qa[0], acc[ns], 0, 0, 0);
            acc[ns] = __builtin_amdgcn_mfma_f32_16x16x32_bf16(kf1, qa[1], acc[ns], 0, 0, 0);
        }
        __builtin_amdgcn_s_setprio(0);

        // V prefetch, ks=1 half (used after softmax)
        bf16x8 vf1[4];
#pragma unroll
        for (int dsb = 0; dsb < 4; ++dsb)
            vf1[dsb] = *(const bf16x8*)(vpt + (size_t)(dsb * 16) * T_SEQ + 32);

        // P = exp(s)/l : store attn + stage bf16 P to LDS, per ns
#pragma unroll
        for (int ns = 0; ns < 4; ++ns) {
            int4 mi = *(const int4*)(mask + k0 + kt * 64 + ns * 16 + lgrp * 4);
            f32x4 mb;
            mb[0] = mi.x ? -1e30f : 0.f;
            mb[1] = mi.y ? -1e30f : 0.f;
            mb[2] = mi.z ? -1e30f : 0.f;
            mb[3] = mi.w ? -1e30f : 0.f;
            f32x4 pv;
#pragma unroll
            for (int rr = 0; rr < 4; ++rr)
                pv[rr] = fexp2(fmaf(acc[ns][rr], L2E, mb[rr])) * rl;
            bf16x4 pb;
            pb[0] = (__bf16)pv[0]; pb[1] = (__bf16)pv[1];
            pb[2] = (__bf16)pv[2]; pb[3] = (__bf16)pv[3];
            *(bf16x4*)(Pw + lrow * 128 + ((ns * 32 + lgrp * 8) ^ swl)) = pb;
            *(f32x4*)(arow + kt * 64 + ns * 16) = pv;
        }

        // O^T += Vt @ P^T   (P same-wave LDS write->read, in-order; V in regs)
        __builtin_amdgcn_s_setprio(1);
        {
            bf16x8 pa0 = *(const bf16x8*)(Pw + lrow * 128 + ((lgrp * 16) ^ swl));
#pragma unroll
            for (int dsb = 0; dsb < 4; ++dsb)
                oacc[dsb] = __builtin_amdgcn_mfma_f32_16x16x32_bf16(vf0[dsb], pa0, oacc[dsb], 0, 0, 0);
            bf16x8 pa1 = *(const bf16x8*)(Pw + lrow * 128 + ((64 + lgrp * 16) ^ swl));
#pragma unroll
            for (int dsb = 0; dsb < 4; ++dsb)
                oacc[dsb] = __builtin_amdgcn_mfma_f32_16x16x32_bf16(vf1[dsb], pa1, oacc[dsb], 0, 0, 0);
        }
        __builtin_amdgcn_s_setprio(0);

        __syncthreads();
        char* tmp = bA; bA = bB; bB = tmp;
    }
#undef STAGE

    // epilogue: lane holds d = dsb*16 + lgrp*4 + rr for q = q0 + w*16 + lrow
    if (of32) {
        float* op = (float*)opart + (size_t)kz * T_SEQ * DMODEL +
                    (size_t)(q0 + w * 16 + lrow) * DMODEL + h * HDIM + lgrp * 4;
#pragma unroll
        for (int dsb = 0; dsb < 4; ++dsb)
            *(f32x4*)(op + dsb * 16) = oacc[dsb];
    } else {
        __bf16* op = (__bf16*)opart + (size_t)(q0 + w * 16 + lrow) * DMODEL + h * HDIM + lgrp * 4;
#pragma unroll
        for (int dsb = 0; dsb < 4; ++dsb) {
            bf16x4 ob;
            ob[0] = (__bf16)oacc[dsb][0]; ob[1] = (__bf16)oacc[dsb][1];
            ob[2] = (__bf16)oacc[dsb][2]; ob[3] = (__bf16)oacc[dsb][3];
            *(bf16x4*)(op + dsb * 16) = ob;
        }
    }
}

// ---------------------------------------------------------------------------
// Kernel 4: output projection.  out = (sum of O partials) @ Wo^T + bo
// ---------------------------------------------------------------------------
__global__ __launch_bounds__(256) void oproj_kernel(
    const void* __restrict__ opart, const float* __restrict__ Wo,
    const float* __restrict__ bo, float* __restrict__ out, int KSP2, int of32)
{
    __shared__ char lds[16384];
    char* Ab = lds;
    char* Bb = lds + 8192;

    const int m0 = blockIdx.x * 64;
    const int n0 = blockIdx.y * 64;
    const int tid  = threadIdx.x;
    const int w    = tid >> 6;
    const int lane = tid & 63;
    const int lrow = lane & 15;
    const int lgrp = lane >> 4;

    f32x4 acc[4] = {};
    const int r   = tid >> 2;
    const int c0e = (tid & 3) * 16;
    const int sw  = (r & 7) << 4;

    for (int kt = 0; kt < 8; ++kt) {
        const int k0 = kt * 64;
        if (of32) {
            const float* p0 = (const float*)opart + (size_t)(m0 + r) * DMODEL + k0 + c0e;
#pragma unroll
            for (int i = 0; i < 4; ++i) {
                f32x4 a4 = *(const f32x4*)(p0 + 4 * i);
                for (int s = 1; s < KSP2; ++s)
                    a4 = a4 + *(const f32x4*)(p0 + (size_t)s * T_SEQ * DMODEL + 4 * i);
                bf16x4 av;
                av[0] = (__bf16)a4[0]; av[1] = (__bf16)a4[1];
                av[2] = (__bf16)a4[2]; av[3] = (__bf16)a4[3];
                *(bf16x4*)(Ab + r * 128 + ((c0e * 2 + 8 * i) ^ sw)) = av;
            }
        } else {
            const __bf16* pa = (const __bf16*)opart + (size_t)(m0 + r) * DMODEL + k0 + c0e;
            bf16x8 a0 = *(const bf16x8*)pa;
            bf16x8 a1 = *(const bf16x8*)(pa + 8);
            *(bf16x8*)(Ab + r * 128 + ((c0e * 2) ^ sw)) = a0;
            *(bf16x8*)(Ab + r * 128 + ((c0e * 2 + 16) ^ sw)) = a1;
        }
        const float* gB = Wo + (size_t)(n0 + r) * DMODEL + k0 + c0e;
#pragma unroll
        for (int i = 0; i < 4; ++i) {
            float4 b4 = *(const float4*)(gB + 4 * i);
            bf16x4 bv4;
            bv4[0] = (__bf16)b4.x; bv4[1] = (__bf16)b4.y;
            bv4[2] = (__bf16)b4.z; bv4[3] = (__bf16)b4.w;
            *(bf16x4*)(Bb + r * 128 + ((c0e * 2 + 8 * i) ^ sw)) = bv4;
        }
        __syncthreads();
#pragma unroll
        for (int ks = 0; ks < 2; ++ks) {
            bf16x8 af = *(const bf16x8*)(Ab + (w * 16 + lrow) * 128 +
                                         ((ks * 64 + lgrp * 16) ^ ((lrow & 7) << 4)));
#pragma unroll
            for (int ns = 0; ns < 4; ++ns) {
                bf16x8 bf = *(const bf16x8*)(Bb + (ns * 16 + lrow) * 128 +
                                             ((ks * 64 + lgrp * 16) ^ ((lrow & 7) << 4)));
                acc[ns] = __builtin_amdgcn_mfma_f32_16x16x32_bf16(af, bf, acc[ns], 0, 0, 0);
            }
        }
        __syncthreads();
    }

#pragma unroll
    for (int ns = 0; ns < 4; ++ns) {
        float bcol = bo[n0 + ns * 16 + lrow];
#pragma unroll
        for (int rr = 0; rr < 4; ++rr) {
            int orow = m0 + w * 16 + lgrp * 4 + rr;
            out[(size_t)orow * DMODEL + n0 + ns * 16 + lrow] = acc[ns][rr] + bcol;
        }
    }
}

// ---------------------------------------------------------------------------
extern "C" void kernel_launch(void* const* d_in, const int* in_sizes, int n_in,
                              void* d_out, int out_size, void* d_ws, size_t ws_size,
                              hipStream_t stream) {
    const float* query = (const float*)d_in[0];
    const float* key   = (const float*)d_in[1];
    const float* value = (const float*)d_in[2];
    const int*   mask  = (const int*)d_in[3];
    const float* Wq = (const float*)d_in[4];
    const float* bq = (const float*)d_in[5];
    const float* Wk = (const float*)d_in[6];
    const float* bk = (const float*)d_in[7];
    const float* Wv = (const float*)d_in[8];
    const float* bv = (const float*)d_in[9];
    const float* Wo = (const float*)d_in[10];
    const float* bo = (const float*)d_in[11];

    float* out  = (float*)d_out;
    float* attn = out + (size_t)T_SEQ * DMODEL;

    char* ws = (char*)d_ws;
    __bf16* qo     = (__bf16*)(ws);
    __bf16* ko     = (__bf16*)(ws + (4u << 20));
    __bf16* vt     = (__bf16*)(ws + (8u << 20));
    float*  l_part = (float*)(ws + (12u << 20));                  // 512 KB
    void*   opart  = (void*)(ws + (12u << 20) + (1u << 19));
    const size_t obase = (12u << 20) + (1u << 19);

    int KSP2, of32;
    const size_t oslice = (size_t)T_SEQ * DMODEL * 4;             // 8 MB f32
    if (ws_size >= obase + 2 * oslice)      { KSP2 = 2; of32 = 1; }
    else if (ws_size >= obase + oslice)     { KSP2 = 1; of32 = 1; }
    else                                    { KSP2 = 1; of32 = 0; }

    qkv_kernel<<<dim3(64, 8, 3), 256, 0, stream>>>(query, key, value,
                                                   Wq, bq, Wk, bk, Wv, bv, qo, ko, vt);
    attn_stats<<<dim3(32 * NH * KS1), 256, 0, stream>>>(qo, ko, mask, l_part);
    attn_main<<<dim3(64 * NH * KSP2), 256, 0, stream>>>(qo, ko, vt, mask, l_part,
                                                        attn, opart, KSP2, of32);
    oproj_kernel<<<dim3(64, 8), 256, 0, stream>>>(opart, Wo, bo, out, KSP2, of32);
}

// Round 11
// 242.753 us; speedup vs baseline: 1.1894x; 1.1894x over previous
//
#include <hip/hip_runtime.h>
#include <hip/hip_bf16.h>
#include <float.h>
#include <stdint.h>

typedef __bf16 bf16x8 __attribute__((ext_vector_type(8)));
typedef __bf16 bf16x4 __attribute__((ext_vector_type(4)));
typedef float  f32x4  __attribute__((ext_vector_type(4)));

#define T_SEQ 4096
#define DMODEL 512
#define NH 8
#define HDIM 64
#define KS1 4                       // k-splits in stats pass
#define L2E 1.44269504088896340736f

__device__ __forceinline__ float fexp2(float x) { return __builtin_amdgcn_exp2f(x); }

// async global->LDS, 16B per lane.  LDS dest is wave-uniform base + lane*16;
// global source is per-lane (pre-swizzled so linear LDS slots get swizzled data).
__device__ __forceinline__ void gl_lds16(const __bf16* g, char* l) {
    __builtin_amdgcn_global_load_lds(
        (const __attribute__((address_space(1))) unsigned int*)(g),
        (__attribute__((address_space(3))) unsigned int*)(l),
        16, 0, 0);
}

// ---------------------------------------------------------------------------
// Kernel 1: fused QKV projection.  q scaled by 1/8; V written TRANSPOSED
// (vt[feature][seq]) for pass-2 staging.
// ---------------------------------------------------------------------------
__global__ __launch_bounds__(256) void qkv_kernel(
    const float* __restrict__ qin, const float* __restrict__ kin, const float* __restrict__ vin,
    const float* __restrict__ Wq, const float* __restrict__ bq,
    const float* __restrict__ Wk, const float* __restrict__ bk,
    const float* __restrict__ Wv, const float* __restrict__ bv,
    __bf16* __restrict__ qo, __bf16* __restrict__ ko, __bf16* __restrict__ vt)
{
    __shared__ char lds[16384];
    char* Ab = lds;
    char* Bb = lds + 8192;

    const int z = blockIdx.z;
    const float* X    = (z == 0) ? qin : (z == 1) ? kin : vin;
    const float* W    = (z == 0) ? Wq  : (z == 1) ? Wk  : Wv;
    const float* bias = (z == 0) ? bq  : (z == 1) ? bk  : bv;

    const int m0 = blockIdx.x * 64;
    const int n0 = blockIdx.y * 64;
    const int tid  = threadIdx.x;
    const int w    = tid >> 6;
    const int lane = tid & 63;
    const int lrow = lane & 15;
    const int lgrp = lane >> 4;

    f32x4 acc[4] = {};
    const int r  = tid >> 2;
    const int c0 = (tid & 3) * 16;

    for (int kt = 0; kt < 8; ++kt) {
        const int k0 = kt * 64;
        const float* gA = X + (size_t)(m0 + r) * DMODEL + k0 + c0;
        const float* gB = W + (size_t)(n0 + r) * DMODEL + k0 + c0;
        const int sw = (r & 7) << 4;
#pragma unroll
        for (int i = 0; i < 4; ++i) {
            float4 a4 = *(const float4*)(gA + 4 * i);
            float4 b4 = *(const float4*)(gB + 4 * i);
            bf16x4 av, bv4;
            av[0] = (__bf16)a4.x; av[1] = (__bf16)a4.y; av[2] = (__bf16)a4.z; av[3] = (__bf16)a4.w;
            bv4[0] = (__bf16)b4.x; bv4[1] = (__bf16)b4.y; bv4[2] = (__bf16)b4.z; bv4[3] = (__bf16)b4.w;
            *(bf16x4*)(Ab + r * 128 + ((c0 * 2 + 8 * i) ^ sw)) = av;
            *(bf16x4*)(Bb + r * 128 + ((c0 * 2 + 8 * i) ^ sw)) = bv4;
        }
        __syncthreads();
#pragma unroll
        for (int ks = 0; ks < 2; ++ks) {
            bf16x8 af = *(const bf16x8*)(Ab + (w * 16 + lrow) * 128 +
                                         ((ks * 64 + lgrp * 16) ^ ((lrow & 7) << 4)));
#pragma unroll
            for (int ns = 0; ns < 4; ++ns) {
                bf16x8 bf = *(const bf16x8*)(Bb + (ns * 16 + lrow) * 128 +
                                             ((ks * 64 + lgrp * 16) ^ ((lrow & 7) << 4)));
                acc[ns] = __builtin_amdgcn_mfma_f32_16x16x32_bf16(af, bf, acc[ns], 0, 0, 0);
            }
        }
        __syncthreads();
    }

    if (z == 2) {
        // transpose epilogue via LDS: LT[col][row], granule swizzle on col
        char* LT = lds;
#pragma unroll
        for (int ns = 0; ns < 4; ++ns) {
            float bcol = bias[n0 + ns * 16 + lrow];
#pragma unroll
            for (int rr = 0; rr < 4; ++rr) {
                int col = ns * 16 + lrow;
                int row = w * 16 + lgrp * 4 + rr;
                *(__bf16*)(LT + col * 128 + ((row * 2) ^ ((col & 7) << 4))) =
                    (__bf16)(acc[ns][rr] + bcol);
            }
        }
        __syncthreads();
        int d  = tid >> 2;
        int nb = (tid & 3) * 32;
        bf16x8 t0 = *(const bf16x8*)(LT + d * 128 + (nb ^ ((d & 7) << 4)));
        bf16x8 t1 = *(const bf16x8*)(LT + d * 128 + ((nb + 16) ^ ((d & 7) << 4)));
        __bf16* dst = vt + (size_t)(n0 + d) * T_SEQ + m0 + (tid & 3) * 16;
        *(bf16x8*)dst = t0;
        *(bf16x8*)(dst + 8) = t1;
    } else {
        __bf16* out = (z == 0) ? qo : ko;
        const float sc = (z == 0) ? 0.125f : 1.0f;   // fold 1/sqrt(HD) into Q (exact)
#pragma unroll
        for (int ns = 0; ns < 4; ++ns) {
            float bcol = bias[n0 + ns * 16 + lrow];
#pragma unroll
            for (int rr = 0; rr < 4; ++rr) {
                int orow = m0 + w * 16 + lgrp * 4 + rr;
                out[(size_t)orow * DMODEL + n0 + ns * 16 + lrow] =
                    (__bf16)((acc[ns][rr] + bcol) * sc);
            }
        }
    }
}

// ---------------------------------------------------------------------------
// Kernel 2: softmax denominators, QBLK=128 (proven R9).  WG = 128 q-rows;
// each wave owns 32 (2x16 subtiles).  K staged in LDS dbuf, shared by 4 waves.
// ---------------------------------------------------------------------------
__global__ __launch_bounds__(256) void attn_stats(
    const __bf16* __restrict__ qb, const __bf16* __restrict__ kb,
    const int* __restrict__ mask, float* __restrict__ l_part)
{
    __shared__ char lds[16384];
    char* KB0 = lds;
    char* KB1 = lds + 8192;

    const int nwg  = 32 * NH * KS1;                     // 1024
    const int b    = blockIdx.x;
    const int rmap = (b & 7) * (nwg >> 3) + (b >> 3);   // XCD-chunked
    const int qsi  = rmap & 31;
    const int h    = (rmap >> 5) & (NH - 1);
    const int ksp  = rmap >> 8;
    const int q0   = qsi * 128;
    const int k0   = ksp * (T_SEQ / KS1);

    const int tid  = threadIdx.x;
    const int w    = tid >> 6;
    const int lane = tid & 63;
    const int lrow = lane & 15;
    const int lgrp = lane >> 4;
    const int swl  = (lrow & 7) << 4;
    const int q0w  = q0 + w * 32;

    bf16x8 qa[2][2];
#pragma unroll
    for (int q2 = 0; q2 < 2; ++q2) {
        const __bf16* qp = qb + (size_t)(q0w + q2 * 16 + lrow) * DMODEL + h * HDIM;
        qa[q2][0] = *(const bf16x8*)(qp + lgrp * 8);
        qa[q2][1] = *(const bf16x8*)(qp + 32 + lgrp * 8);
    }

    // staging source (pre-swizzled): lane slot -> (key, granule)
    const int key0 = w * 16 + (lane >> 3);
    const int key1 = key0 + 8;
    const int g    = lane & 7;
    const __bf16* sK0 = kb + (size_t)(k0 + key0) * DMODEL + h * HDIM + (g ^ (key0 & 7)) * 8;
    const __bf16* sK1 = kb + (size_t)(k0 + key1) * DMODEL + h * HDIM + (g ^ (key1 & 7)) * 8;

    float lsum[2][4] = {};

    gl_lds16(sK0, KB0 + w * 2048);
    gl_lds16(sK1, KB0 + w * 2048 + 1024);
    __syncthreads();

    char* cur = KB0;
    char* nxt = KB1;
    const int NT = (T_SEQ / KS1) / 64;   // 16
    for (int kt = 0; kt < NT; ++kt) {
        if (kt + 1 < NT) {
            gl_lds16(sK0 + (size_t)(kt + 1) * 64 * DMODEL, nxt + w * 2048);
            gl_lds16(sK1 + (size_t)(kt + 1) * 64 * DMODEL, nxt + w * 2048 + 1024);
        }

        f32x4 acc[2][4] = {};
        __builtin_amdgcn_s_setprio(1);
#pragma unroll
        for (int ns = 0; ns < 4; ++ns) {
            bf16x8 kf0 = *(const bf16x8*)(cur + (ns * 16 + lrow) * 128 + ((lgrp * 16) ^ swl));
            bf16x8 kf1 = *(const bf16x8*)(cur + (ns * 16 + lrow) * 128 + ((64 + lgrp * 16) ^ swl));
            acc[0][ns] = __builtin_amdgcn_mfma_f32_16x16x32_bf16(kf0, qa[0][0], acc[0][ns], 0, 0, 0);
            acc[0][ns] = __builtin_amdgcn_mfma_f32_16x16x32_bf16(kf1, qa[0][1], acc[0][ns], 0, 0, 0);
            acc[1][ns] = __builtin_amdgcn_mfma_f32_16x16x32_bf16(kf0, qa[1][0], acc[1][ns], 0, 0, 0);
            acc[1][ns] = __builtin_amdgcn_mfma_f32_16x16x32_bf16(kf1, qa[1][1], acc[1][ns], 0, 0, 0);
        }
        __builtin_amdgcn_s_setprio(0);

#pragma unroll
        for (int ns = 0; ns < 4; ++ns) {
            int4 mi = *(const int4*)(mask + k0 + kt * 64 + ns * 16 + lgrp * 4);
            f32x4 mb;
            mb[0] = mi.x ? -1e30f : 0.f;
            mb[1] = mi.y ? -1e30f : 0.f;
            mb[2] = mi.z ? -1e30f : 0.f;
            mb[3] = mi.w ? -1e30f : 0.f;
#pragma unroll
            for (int q2 = 0; q2 < 2; ++q2)
#pragma unroll
                for (int rr = 0; rr < 4; ++rr)
                    lsum[q2][ns] += fexp2(fmaf(acc[q2][ns][rr], L2E, mb[rr]));
        }
        __syncthreads();
        char* t = cur; cur = nxt; nxt = t;
    }

#pragma unroll
    for (int q2 = 0; q2 < 2; ++q2) {
        float tot = (lsum[q2][0] + lsum[q2][1]) + (lsum[q2][2] + lsum[q2][3]);
        tot += __shfl_xor(tot, 16);
        tot += __shfl_xor(tot, 32);
        if (lgrp == 0)
            l_part[((size_t)h * KS1 + ksp) * T_SEQ + q0w + q2 * 16 + lrow] = tot;
    }
}

// ---------------------------------------------------------------------------
// Kernel 3: main attention pass (R9 structure) with explicit VMEM issue order
// [mask x4][STAGE x4][stores x4] per iteration (sched_barrier fences) and a
// counted vmcnt(4) + raw s_barrier: mask use retires only masks (prefetch
// floats on); the tile's stores ride across the barrier and drain under the
// next tile's compute.  LDS 40KB -> 4 WG/CU.
// ---------------------------------------------------------------------------
__global__ __launch_bounds__(256) void attn_main(
    const __bf16* __restrict__ qb, const __bf16* __restrict__ kb,
    const __bf16* __restrict__ vt, const int* __restrict__ mask,
    const float* __restrict__ l_part,
    float* __restrict__ attn_out, void* __restrict__ opart,
    int KSP2, int of32)
{
    __shared__ char lds[40960];
    char* PB  = lds + 32768;   // 4 waves x 2 KB

    const int nwg  = 64 * NH * KSP2;
    const int b    = blockIdx.x;
    const int rmap = (b & 7) * (nwg >> 3) + (b >> 3);   // XCD-chunked (nwg%8==0)
    const int qbi  = rmap & 63;
    const int h    = (rmap >> 6) & (NH - 1);
    const int kz   = rmap >> 9;
    const int q0   = qbi * 64;
    const int kspan = T_SEQ / KSP2;
    const int k0   = kz * kspan;
    const int NT   = kspan / 64;

    const int tid  = threadIdx.x;
    const int w    = tid >> 6;
    const int lane = tid & 63;
    const int lrow = lane & 15;
    const int lgrp = lane >> 4;
    const int swl  = (lrow & 7) << 4;

    bf16x8 qa[2];
    {
        const __bf16* qp = qb + (size_t)(q0 + w * 16 + lrow) * DMODEL + h * HDIM;
        qa[0] = *(const bf16x8*)(qp + lgrp * 8);
        qa[1] = *(const bf16x8*)(qp + 32 + lgrp * 8);
    }

    float rl;
    {
        float s = 0.f;
#pragma unroll
        for (int ks = 0; ks < KS1; ++ks)
            s += l_part[((size_t)h * KS1 + ks) * T_SEQ + q0 + w * 16 + lrow];
        rl = 1.0f / s;
    }

    // staging sources (pre-swizzled)
    const int key0 = w * 16 + (lane >> 3);
    const int key1 = key0 + 8;
    const int g    = lane & 7;
    const __bf16* sK0 = kb + (size_t)(k0 + key0) * DMODEL + h * HDIM + (g ^ (key0 & 7)) * 8;
    const __bf16* sK1 = kb + (size_t)(k0 + key1) * DMODEL + h * HDIM + (g ^ (key1 & 7)) * 8;
    const __bf16* sV0 = vt + (size_t)(h * HDIM + key0) * T_SEQ + k0 + (g ^ (key0 & 7)) * 8;
    const __bf16* sV1 = vt + (size_t)(h * HDIM + key1) * T_SEQ + k0 + (g ^ (key1 & 7)) * 8;

#define STAGE(tt, buf) do {                                             \
        size_t koff_ = (size_t)(tt) * 64 * DMODEL;                      \
        size_t voff_ = (size_t)(tt) * 64;                               \
        gl_lds16(sK0 + koff_, (buf) + w * 2048);                        \
        gl_lds16(sK1 + koff_, (buf) + w * 2048 + 1024);                 \
        gl_lds16(sV0 + voff_, (buf) + 8192 + w * 2048);                 \
        gl_lds16(sV1 + voff_, (buf) + 8192 + w * 2048 + 1024);          \
    } while (0)

    f32x4 oacc[4] = {};
    float* arow = attn_out + (size_t)h * T_SEQ * T_SEQ +
                  (size_t)(q0 + w * 16 + lrow) * T_SEQ + k0 + lgrp * 4;
    char* Pw = PB + w * 2048;

    char* bA = lds;
    char* bB = lds + 16384;

    STAGE(0, bA);
    __syncthreads();

    for (int kt = 0; kt < NT; ++kt) {
        // VMEM order pin: masks first, then next-tile STAGE, then (later) stores
        int4 mi[4];
#pragma unroll
        for (int ns = 0; ns < 4; ++ns)
            mi[ns] = *(const int4*)(mask + k0 + kt * 64 + ns * 16 + lgrp * 4);
        __builtin_amdgcn_sched_barrier(0);
        if (kt + 1 < NT) STAGE(kt + 1, bB);
        __builtin_amdgcn_sched_barrier(0);

        f32x4 acc[4] = {};
        __builtin_amdgcn_s_setprio(1);
#pragma unroll
        for (int ns = 0; ns < 4; ++ns) {
            bf16x8 kf0 = *(const bf16x8*)(bA + (ns * 16 + lrow) * 128 + ((lgrp * 16) ^ swl));
            bf16x8 kf1 = *(const bf16x8*)(bA + (ns * 16 + lrow) * 128 + ((64 + lgrp * 16) ^ swl));
            acc[ns] = __builtin_amdgcn_mfma_f32_16x16x32_bf16(kf0, qa[0], acc[ns], 0, 0, 0);
            acc[ns] = __builtin_amdgcn_mfma_f32_16x16x32_bf16(kf1, qa[1], acc[ns], 0, 0, 0);
        }
        __builtin_amdgcn_s_setprio(0);

        // P = exp(s)/l : stage bf16 P to LDS + store attn f32x4 (stores drain
        // across the barrier below)
#pragma unroll
        for (int ns = 0; ns < 4; ++ns) {
            f32x4 mb;
            mb[0] = mi[ns].x ? -1e30f : 0.f;
            mb[1] = mi[ns].y ? -1e30f : 0.f;
            mb[2] = mi[ns].z ? -1e30f : 0.f;
            mb[3] = mi[ns].w ? -1e30f : 0.f;
            f32x4 pv;
#pragma unroll
            for (int rr = 0; rr < 4; ++rr)
                pv[rr] = fexp2(fmaf(acc[ns][rr], L2E, mb[rr])) * rl;
            bf16x4 pb;
            pb[0] = (__bf16)pv[0]; pb[1] = (__bf16)pv[1];
            pb[2] = (__bf16)pv[2]; pb[3] = (__bf16)pv[3];
            *(bf16x4*)(Pw + lrow * 128 + ((ns * 32 + lgrp * 8) ^ swl)) = pb;
            *(f32x4*)(arow + kt * 64 + ns * 16) = pv;
        }

        // O^T += Vt @ P^T   (same-wave LDS write->read, in-order)
        __builtin_amdgcn_s_setprio(1);
#pragma unroll
        for (int ks = 0; ks < 2; ++ks) {
            bf16x8 pa = *(const bf16x8*)(Pw + lrow * 128 + ((ks * 64 + lgrp * 16) ^ swl));
#pragma unroll
            for (int dsb = 0; dsb < 4; ++dsb) {
                bf16x8 vf = *(const bf16x8*)(bA + 8192 + (dsb * 16 + lrow) * 128 +
                                             ((ks * 64 + lgrp * 16) ^ swl));
                oacc[dsb] = __builtin_amdgcn_mfma_f32_16x16x32_bf16(vf, pa, oacc[dsb], 0, 0, 0);
            }
        }
        __builtin_amdgcn_s_setprio(0);

        if (kt + 1 < NT) {
            // In-order VMEM FIFO: [masks retired][STAGE x4][stores x4].
            // vmcnt(4): STAGE(kt+1) complete; this tile's 4 stores linger.
            asm volatile("s_waitcnt vmcnt(4)" ::: "memory");
            __builtin_amdgcn_s_barrier();
            __builtin_amdgcn_sched_barrier(0);
        }
        char* tmp = bA; bA = bB; bB = tmp;
    }
#undef STAGE

    // epilogue: lane holds d = dsb*16 + lgrp*4 + rr for q = q0 + w*16 + lrow
    if (of32) {
        float* op = (float*)opart + (size_t)kz * T_SEQ * DMODEL +
                    (size_t)(q0 + w * 16 + lrow) * DMODEL + h * HDIM + lgrp * 4;
#pragma unroll
        for (int dsb = 0; dsb < 4; ++dsb)
            *(f32x4*)(op + dsb * 16) = oacc[dsb];
    } else {
        __bf16* op = (__bf16*)opart + (size_t)(q0 + w * 16 + lrow) * DMODEL + h * HDIM + lgrp * 4;
#pragma unroll
        for (int dsb = 0; dsb < 4; ++dsb) {
            bf16x4 ob;
            ob[0] = (__bf16)oacc[dsb][0]; ob[1] = (__bf16)oacc[dsb][1];
            ob[2] = (__bf16)oacc[dsb][2]; ob[3] = (__bf16)oacc[dsb][3];
            *(bf16x4*)(op + dsb * 16) = ob;
        }
    }
}

// ---------------------------------------------------------------------------
// Kernel 4: output projection.  out = (sum of O partials) @ Wo^T + bo
// ---------------------------------------------------------------------------
__global__ __launch_bounds__(256) void oproj_kernel(
    const void* __restrict__ opart, const float* __restrict__ Wo,
    const float* __restrict__ bo, float* __restrict__ out, int KSP2, int of32)
{
    __shared__ char lds[16384];
    char* Ab = lds;
    char* Bb = lds + 8192;

    const int m0 = blockIdx.x * 64;
    const int n0 = blockIdx.y * 64;
    const int tid  = threadIdx.x;
    const int w    = tid >> 6;
    const int lane = tid & 63;
    const int lrow = lane & 15;
    const int lgrp = lane >> 4;

    f32x4 acc[4] = {};
    const int r   = tid >> 2;
    const int c0e = (tid & 3) * 16;
    const int sw  = (r & 7) << 4;

    for (int kt = 0; kt < 8; ++kt) {
        const int k0 = kt * 64;
        if (of32) {
            const float* p0 = (const float*)opart + (size_t)(m0 + r) * DMODEL + k0 + c0e;
#pragma unroll
            for (int i = 0; i < 4; ++i) {
                f32x4 a4 = *(const f32x4*)(p0 + 4 * i);
                for (int s = 1; s < KSP2; ++s)
                    a4 = a4 + *(const f32x4*)(p0 + (size_t)s * T_SEQ * DMODEL + 4 * i);
                bf16x4 av;
                av[0] = (__bf16)a4[0]; av[1] = (__bf16)a4[1];
                av[2] = (__bf16)a4[2]; av[3] = (__bf16)a4[3];
                *(bf16x4*)(Ab + r * 128 + ((c0e * 2 + 8 * i) ^ sw)) = av;
            }
        } else {
            const __bf16* pa = (const __bf16*)opart + (size_t)(m0 + r) * DMODEL + k0 + c0e;
            bf16x8 a0 = *(const bf16x8*)pa;
            bf16x8 a1 = *(const bf16x8*)(pa + 8);
            *(bf16x8*)(Ab + r * 128 + ((c0e * 2) ^ sw)) = a0;
            *(bf16x8*)(Ab + r * 128 + ((c0e * 2 + 16) ^ sw)) = a1;
        }
        const float* gB = Wo + (size_t)(n0 + r) * DMODEL + k0 + c0e;
#pragma unroll
        for (int i = 0; i < 4; ++i) {
            float4 b4 = *(const float4*)(gB + 4 * i);
            bf16x4 bv4;
            bv4[0] = (__bf16)b4.x; bv4[1] = (__bf16)b4.y;
            bv4[2] = (__bf16)b4.z; bv4[3] = (__bf16)b4.w;
            *(bf16x4*)(Bb + r * 128 + ((c0e * 2 + 8 * i) ^ sw)) = bv4;
        }
        __syncthreads();
#pragma unroll
        for (int ks = 0; ks < 2; ++ks) {
            bf16x8 af = *(const bf16x8*)(Ab + (w * 16 + lrow) * 128 +
                                         ((ks * 64 + lgrp * 16) ^ ((lrow & 7) << 4)));
#pragma unroll
            for (int ns = 0; ns < 4; ++ns) {
                bf16x8 bf = *(const bf16x8*)(Bb + (ns * 16 + lrow) * 128 +
                                             ((ks * 64 + lgrp * 16) ^ ((lrow & 7) << 4)));
                acc[ns] = __builtin_amdgcn_mfma_f32_16x16x32_bf16(af, bf, acc[ns], 0, 0, 0);
            }
        }
        __syncthreads();
    }

#pragma unroll
    for (int ns = 0; ns < 4; ++ns) {
        float bcol = bo[n0 + ns * 16 + lrow];
#pragma unroll
        for (int rr = 0; rr < 4; ++rr) {
            int orow = m0 + w * 16 + lgrp * 4 + rr;
            out[(size_t)orow * DMODEL + n0 + ns * 16 + lrow] = acc[ns][rr] + bcol;
        }
    }
}

// ---------------------------------------------------------------------------
extern "C" void kernel_launch(void* const* d_in, const int* in_sizes, int n_in,
                              void* d_out, int out_size, void* d_ws, size_t ws_size,
                              hipStream_t stream) {
    const float* query = (const float*)d_in[0];
    const float* key   = (const float*)d_in[1];
    const float* value = (const float*)d_in[2];
    const int*   mask  = (const int*)d_in[3];
    const float* Wq = (const float*)d_in[4];
    const float* bq = (const float*)d_in[5];
    const float* Wk = (const float*)d_in[6];
    const float* bk = (const float*)d_in[7];
    const float* Wv = (const float*)d_in[8];
    const float* bv = (const float*)d_in[9];
    const float* Wo = (const float*)d_in[10];
    const float* bo = (const float*)d_in[11];

    float* out  = (float*)d_out;
    float* attn = out + (size_t)T_SEQ * DMODEL;

    char* ws = (char*)d_ws;
    __bf16* qo     = (__bf16*)(ws);
    __bf16* ko     = (__bf16*)(ws + (4u << 20));
    __bf16* vt     = (__bf16*)(ws + (8u << 20));
    float*  l_part = (float*)(ws + (12u << 20));                  // 512 KB
    void*   opart  = (void*)(ws + (12u << 20) + (1u << 19));
    const size_t obase = (12u << 20) + (1u << 19);

    int KSP2, of32;
    const size_t oslice = (size_t)T_SEQ * DMODEL * 4;             // 8 MB f32
    if (ws_size >= obase + 2 * oslice)      { KSP2 = 2; of32 = 1; }
    else if (ws_size >= obase + oslice)     { KSP2 = 1; of32 = 1; }
    else                                    { KSP2 = 1; of32 = 0; }

    qkv_kernel<<<dim3(64, 8, 3), 256, 0, stream>>>(query, key, value,
                                                   Wq, bq, Wk, bk, Wv, bv, qo, ko, vt);
    attn_stats<<<dim3(32 * NH * KS1), 256, 0, stream>>>(qo, ko, mask, l_part);
    attn_main<<<dim3(64 * NH * KSP2), 256, 0, stream>>>(qo, ko, vt, mask, l_part,
                                                        attn, opart, KSP2, of32);
    oproj_kernel<<<dim3(64, 8), 256, 0, stream>>>(opart, Wo, bo, out, KSP2, of32);
}

// Round 12
// 232.711 us; speedup vs baseline: 1.2407x; 1.0432x over previous
//
#include <hip/hip_runtime.h>
#include <hip/hip_bf16.h>
#include <float.h>
#include <stdint.h>

typedef __bf16 bf16x8 __attribute__((ext_vector_type(8)));
typedef __bf16 bf16x4 __attribute__((ext_vector_type(4)));
typedef float  f32x4  __attribute__((ext_vector_type(4)));

#define T_SEQ 4096
#define DMODEL 512
#define NH 8
#define HDIM 64
#define KS1 4                       // k-splits in stats pass
#define L2E 1.44269504088896340736f

__device__ __forceinline__ float fexp2(float x) { return __builtin_amdgcn_exp2f(x); }

// async global->LDS, 16B per lane.  LDS dest is wave-uniform base + lane*16;
// global source is per-lane (pre-swizzled so linear LDS slots get swizzled data).
__device__ __forceinline__ void gl_lds16(const __bf16* g, char* l) {
    __builtin_amdgcn_global_load_lds(
        (const __attribute__((address_space(1))) unsigned int*)(g),
        (__attribute__((address_space(3))) unsigned int*)(l),
        16, 0, 0);
}

// ---------------------------------------------------------------------------
// Kernel 1: fused QKV projection.  q scaled by 1/8; V written TRANSPOSED
// (vt[feature][seq]) for pass-2 staging.
// ---------------------------------------------------------------------------
__global__ __launch_bounds__(256) void qkv_kernel(
    const float* __restrict__ qin, const float* __restrict__ kin, const float* __restrict__ vin,
    const float* __restrict__ Wq, const float* __restrict__ bq,
    const float* __restrict__ Wk, const float* __restrict__ bk,
    const float* __restrict__ Wv, const float* __restrict__ bv,
    __bf16* __restrict__ qo, __bf16* __restrict__ ko, __bf16* __restrict__ vt)
{
    __shared__ char lds[16384];
    char* Ab = lds;
    char* Bb = lds + 8192;

    const int z = blockIdx.z;
    const float* X    = (z == 0) ? qin : (z == 1) ? kin : vin;
    const float* W    = (z == 0) ? Wq  : (z == 1) ? Wk  : Wv;
    const float* bias = (z == 0) ? bq  : (z == 1) ? bk  : bv;

    const int m0 = blockIdx.x * 64;
    const int n0 = blockIdx.y * 64;
    const int tid  = threadIdx.x;
    const int w    = tid >> 6;
    const int lane = tid & 63;
    const int lrow = lane & 15;
    const int lgrp = lane >> 4;

    f32x4 acc[4] = {};
    const int r  = tid >> 2;
    const int c0 = (tid & 3) * 16;

    for (int kt = 0; kt < 8; ++kt) {
        const int k0 = kt * 64;
        const float* gA = X + (size_t)(m0 + r) * DMODEL + k0 + c0;
        const float* gB = W + (size_t)(n0 + r) * DMODEL + k0 + c0;
        const int sw = (r & 7) << 4;
#pragma unroll
        for (int i = 0; i < 4; ++i) {
            float4 a4 = *(const float4*)(gA + 4 * i);
            float4 b4 = *(const float4*)(gB + 4 * i);
            bf16x4 av, bv4;
            av[0] = (__bf16)a4.x; av[1] = (__bf16)a4.y; av[2] = (__bf16)a4.z; av[3] = (__bf16)a4.w;
            bv4[0] = (__bf16)b4.x; bv4[1] = (__bf16)b4.y; bv4[2] = (__bf16)b4.z; bv4[3] = (__bf16)b4.w;
            *(bf16x4*)(Ab + r * 128 + ((c0 * 2 + 8 * i) ^ sw)) = av;
            *(bf16x4*)(Bb + r * 128 + ((c0 * 2 + 8 * i) ^ sw)) = bv4;
        }
        __syncthreads();
#pragma unroll
        for (int ks = 0; ks < 2; ++ks) {
            bf16x8 af = *(const bf16x8*)(Ab + (w * 16 + lrow) * 128 +
                                         ((ks * 64 + lgrp * 16) ^ ((lrow & 7) << 4)));
#pragma unroll
            for (int ns = 0; ns < 4; ++ns) {
                bf16x8 bf = *(const bf16x8*)(Bb + (ns * 16 + lrow) * 128 +
                                             ((ks * 64 + lgrp * 16) ^ ((lrow & 7) << 4)));
                acc[ns] = __builtin_amdgcn_mfma_f32_16x16x32_bf16(af, bf, acc[ns], 0, 0, 0);
            }
        }
        __syncthreads();
    }

    if (z == 2) {
        // transpose epilogue via LDS: LT[col][row], granule swizzle on col
        char* LT = lds;
#pragma unroll
        for (int ns = 0; ns < 4; ++ns) {
            float bcol = bias[n0 + ns * 16 + lrow];
#pragma unroll
            for (int rr = 0; rr < 4; ++rr) {
                int col = ns * 16 + lrow;
                int row = w * 16 + lgrp * 4 + rr;
                *(__bf16*)(LT + col * 128 + ((row * 2) ^ ((col & 7) << 4))) =
                    (__bf16)(acc[ns][rr] + bcol);
            }
        }
        __syncthreads();
        int d  = tid >> 2;
        int nb = (tid & 3) * 32;
        bf16x8 t0 = *(const bf16x8*)(LT + d * 128 + (nb ^ ((d & 7) << 4)));
        bf16x8 t1 = *(const bf16x8*)(LT + d * 128 + ((nb + 16) ^ ((d & 7) << 4)));
        __bf16* dst = vt + (size_t)(n0 + d) * T_SEQ + m0 + (tid & 3) * 16;
        *(bf16x8*)dst = t0;
        *(bf16x8*)(dst + 8) = t1;
    } else {
        __bf16* out = (z == 0) ? qo : ko;
        const float sc = (z == 0) ? 0.125f : 1.0f;   // fold 1/sqrt(HD) into Q (exact)
#pragma unroll
        for (int ns = 0; ns < 4; ++ns) {
            float bcol = bias[n0 + ns * 16 + lrow];
#pragma unroll
            for (int rr = 0; rr < 4; ++rr) {
                int orow = m0 + w * 16 + lgrp * 4 + rr;
                out[(size_t)orow * DMODEL + n0 + ns * 16 + lrow] =
                    (__bf16)((acc[ns][rr] + bcol) * sc);
            }
        }
    }
}

// ---------------------------------------------------------------------------
// Kernel 2: softmax denominators, QBLK=128 (proven R9).  WG = 128 q-rows;
// each wave owns 32 (2x16 subtiles).  K staged in LDS dbuf, shared by 4 waves.
// ---------------------------------------------------------------------------
__global__ __launch_bounds__(256) void attn_stats(
    const __bf16* __restrict__ qb, const __bf16* __restrict__ kb,
    const int* __restrict__ mask, float* __restrict__ l_part)
{
    __shared__ char lds[16384];
    char* KB0 = lds;
    char* KB1 = lds + 8192;

    const int nwg  = 32 * NH * KS1;                     // 1024
    const int b    = blockIdx.x;
    const int rmap = (b & 7) * (nwg >> 3) + (b >> 3);   // XCD-chunked
    const int qsi  = rmap & 31;
    const int h    = (rmap >> 5) & (NH - 1);
    const int ksp  = rmap >> 8;
    const int q0   = qsi * 128;
    const int k0   = ksp * (T_SEQ / KS1);

    const int tid  = threadIdx.x;
    const int w    = tid >> 6;
    const int lane = tid & 63;
    const int lrow = lane & 15;
    const int lgrp = lane >> 4;
    const int swl  = (lrow & 7) << 4;
    const int q0w  = q0 + w * 32;

    bf16x8 qa[2][2];
#pragma unroll
    for (int q2 = 0; q2 < 2; ++q2) {
        const __bf16* qp = qb + (size_t)(q0w + q2 * 16 + lrow) * DMODEL + h * HDIM;
        qa[q2][0] = *(const bf16x8*)(qp + lgrp * 8);
        qa[q2][1] = *(const bf16x8*)(qp + 32 + lgrp * 8);
    }

    // staging source (pre-swizzled): lane slot -> (key, granule)
    const int key0 = w * 16 + (lane >> 3);
    const int key1 = key0 + 8;
    const int g    = lane & 7;
    const __bf16* sK0 = kb + (size_t)(k0 + key0) * DMODEL + h * HDIM + (g ^ (key0 & 7)) * 8;
    const __bf16* sK1 = kb + (size_t)(k0 + key1) * DMODEL + h * HDIM + (g ^ (key1 & 7)) * 8;

    float lsum[2][4] = {};

    gl_lds16(sK0, KB0 + w * 2048);
    gl_lds16(sK1, KB0 + w * 2048 + 1024);
    __syncthreads();

    char* cur = KB0;
    char* nxt = KB1;
    const int NT = (T_SEQ / KS1) / 64;   // 16
    for (int kt = 0; kt < NT; ++kt) {
        if (kt + 1 < NT) {
            gl_lds16(sK0 + (size_t)(kt + 1) * 64 * DMODEL, nxt + w * 2048);
            gl_lds16(sK1 + (size_t)(kt + 1) * 64 * DMODEL, nxt + w * 2048 + 1024);
        }

        f32x4 acc[2][4] = {};
        __builtin_amdgcn_s_setprio(1);
#pragma unroll
        for (int ns = 0; ns < 4; ++ns) {
            bf16x8 kf0 = *(const bf16x8*)(cur + (ns * 16 + lrow) * 128 + ((lgrp * 16) ^ swl));
            bf16x8 kf1 = *(const bf16x8*)(cur + (ns * 16 + lrow) * 128 + ((64 + lgrp * 16) ^ swl));
            acc[0][ns] = __builtin_amdgcn_mfma_f32_16x16x32_bf16(kf0, qa[0][0], acc[0][ns], 0, 0, 0);
            acc[0][ns] = __builtin_amdgcn_mfma_f32_16x16x32_bf16(kf1, qa[0][1], acc[0][ns], 0, 0, 0);
            acc[1][ns] = __builtin_amdgcn_mfma_f32_16x16x32_bf16(kf0, qa[1][0], acc[1][ns], 0, 0, 0);
            acc[1][ns] = __builtin_amdgcn_mfma_f32_16x16x32_bf16(kf1, qa[1][1], acc[1][ns], 0, 0, 0);
        }
        __builtin_amdgcn_s_setprio(0);

#pragma unroll
        for (int ns = 0; ns < 4; ++ns) {
            int4 mi = *(const int4*)(mask + k0 + kt * 64 + ns * 16 + lgrp * 4);
            f32x4 mb;
            mb[0] = mi.x ? -1e30f : 0.f;
            mb[1] = mi.y ? -1e30f : 0.f;
            mb[2] = mi.z ? -1e30f : 0.f;
            mb[3] = mi.w ? -1e30f : 0.f;
#pragma unroll
            for (int q2 = 0; q2 < 2; ++q2)
#pragma unroll
                for (int rr = 0; rr < 4; ++rr)
                    lsum[q2][ns] += fexp2(fmaf(acc[q2][ns][rr], L2E, mb[rr]));
        }
        __syncthreads();
        char* t = cur; cur = nxt; nxt = t;
    }

#pragma unroll
    for (int q2 = 0; q2 < 2; ++q2) {
        float tot = (lsum[q2][0] + lsum[q2][1]) + (lsum[q2][2] + lsum[q2][3]);
        tot += __shfl_xor(tot, 16);
        tot += __shfl_xor(tot, 32);
        if (lgrp == 0)
            l_part[((size_t)h * KS1 + ksp) * T_SEQ + q0w + q2 * 16 + lrow] = tot;
    }
}

// ---------------------------------------------------------------------------
// Kernel 3: main attention pass (R9 structure) with CROSS-TILE deferred attn
// stores: tile kt's 4 f32x4 rows are held in registers across the barrier and
// issued at the top of tile kt+1 -- the stores get a full tile of compute to
// drain before the next __syncthreads.  No vmcnt counting, no sched pins.
// LDS 40KB -> 4 WG/CU.
// ---------------------------------------------------------------------------
__global__ __launch_bounds__(256) void attn_main(
    const __bf16* __restrict__ qb, const __bf16* __restrict__ kb,
    const __bf16* __restrict__ vt, const int* __restrict__ mask,
    const float* __restrict__ l_part,
    float* __restrict__ attn_out, void* __restrict__ opart,
    int KSP2, int of32)
{
    __shared__ char lds[40960];
    char* PB  = lds + 32768;   // 4 waves x 2 KB

    const int nwg  = 64 * NH * KSP2;
    const int b    = blockIdx.x;
    const int rmap = (b & 7) * (nwg >> 3) + (b >> 3);   // XCD-chunked (nwg%8==0)
    const int qbi  = rmap & 63;
    const int h    = (rmap >> 6) & (NH - 1);
    const int kz   = rmap >> 9;
    const int q0   = qbi * 64;
    const int kspan = T_SEQ / KSP2;
    const int k0   = kz * kspan;
    const int NT   = kspan / 64;

    const int tid  = threadIdx.x;
    const int w    = tid >> 6;
    const int lane = tid & 63;
    const int lrow = lane & 15;
    const int lgrp = lane >> 4;
    const int swl  = (lrow & 7) << 4;

    bf16x8 qa[2];
    {
        const __bf16* qp = qb + (size_t)(q0 + w * 16 + lrow) * DMODEL + h * HDIM;
        qa[0] = *(const bf16x8*)(qp + lgrp * 8);
        qa[1] = *(const bf16x8*)(qp + 32 + lgrp * 8);
    }

    float rl;
    {
        float s = 0.f;
#pragma unroll
        for (int ks = 0; ks < KS1; ++ks)
            s += l_part[((size_t)h * KS1 + ks) * T_SEQ + q0 + w * 16 + lrow];
        rl = 1.0f / s;
    }

    // staging sources (pre-swizzled)
    const int key0 = w * 16 + (lane >> 3);
    const int key1 = key0 + 8;
    const int g    = lane & 7;
    const __bf16* sK0 = kb + (size_t)(k0 + key0) * DMODEL + h * HDIM + (g ^ (key0 & 7)) * 8;
    const __bf16* sK1 = kb + (size_t)(k0 + key1) * DMODEL + h * HDIM + (g ^ (key1 & 7)) * 8;
    const __bf16* sV0 = vt + (size_t)(h * HDIM + key0) * T_SEQ + k0 + (g ^ (key0 & 7)) * 8;
    const __bf16* sV1 = vt + (size_t)(h * HDIM + key1) * T_SEQ + k0 + (g ^ (key1 & 7)) * 8;

#define STAGE(tt, buf) do {                                             \
        size_t koff_ = (size_t)(tt) * 64 * DMODEL;                      \
        size_t voff_ = (size_t)(tt) * 64;                               \
        gl_lds16(sK0 + koff_, (buf) + w * 2048);                        \
        gl_lds16(sK1 + koff_, (buf) + w * 2048 + 1024);                 \
        gl_lds16(sV0 + voff_, (buf) + 8192 + w * 2048);                 \
        gl_lds16(sV1 + voff_, (buf) + 8192 + w * 2048 + 1024);          \
    } while (0)

    f32x4 oacc[4] = {};
    float* arow = attn_out + (size_t)h * T_SEQ * T_SEQ +
                  (size_t)(q0 + w * 16 + lrow) * T_SEQ + k0 + lgrp * 4;
    char* Pw = PB + w * 2048;

    char* bA = lds;
    char* bB = lds + 16384;

    STAGE(0, bA);
    __syncthreads();

    f32x4 pvs[4];   // previous tile's normalized rows, stored one tile late

    for (int kt = 0; kt < NT; ++kt) {
        if (kt + 1 < NT) STAGE(kt + 1, bB);

        // deferred attn stores for tile kt-1 (drain during this whole tile)
        if (kt > 0) {
#pragma unroll
            for (int ns = 0; ns < 4; ++ns)
                *(f32x4*)(arow + (kt - 1) * 64 + ns * 16) = pvs[ns];
        }

        f32x4 acc[4] = {};
        __builtin_amdgcn_s_setprio(1);
#pragma unroll
        for (int ns = 0; ns < 4; ++ns) {
            bf16x8 kf0 = *(const bf16x8*)(bA + (ns * 16 + lrow) * 128 + ((lgrp * 16) ^ swl));
            bf16x8 kf1 = *(const bf16x8*)(bA + (ns * 16 + lrow) * 128 + ((64 + lgrp * 16) ^ swl));
            acc[ns] = __builtin_amdgcn_mfma_f32_16x16x32_bf16(kf0, qa[0], acc[ns], 0, 0, 0);
            acc[ns] = __builtin_amdgcn_mfma_f32_16x16x32_bf16(kf1, qa[1], acc[ns], 0, 0, 0);
        }
        __builtin_amdgcn_s_setprio(0);

        // P = exp(s)/l : stage bf16 P to LDS, keep f32x4 rows for next-tile store
#pragma unroll
        for (int ns = 0; ns < 4; ++ns) {
            int4 mi = *(const int4*)(mask + k0 + kt * 64 + ns * 16 + lgrp * 4);
            f32x4 mb;
            mb[0] = mi.x ? -1e30f : 0.f;
            mb[1] = mi.y ? -1e30f : 0.f;
            mb[2] = mi.z ? -1e30f : 0.f;
            mb[3] = mi.w ? -1e30f : 0.f;
            f32x4 pv;
#pragma unroll
            for (int rr = 0; rr < 4; ++rr)
                pv[rr] = fexp2(fmaf(acc[ns][rr], L2E, mb[rr])) * rl;
            pvs[ns] = pv;
            bf16x4 pb;
            pb[0] = (__bf16)pv[0]; pb[1] = (__bf16)pv[1];
            pb[2] = (__bf16)pv[2]; pb[3] = (__bf16)pv[3];
            *(bf16x4*)(Pw + lrow * 128 + ((ns * 32 + lgrp * 8) ^ swl)) = pb;
        }

        // O^T += Vt @ P^T   (same-wave LDS write->read, in-order)
        __builtin_amdgcn_s_setprio(1);
#pragma unroll
        for (int ks = 0; ks < 2; ++ks) {
            bf16x8 pa = *(const bf16x8*)(Pw + lrow * 128 + ((ks * 64 + lgrp * 16) ^ swl));
#pragma unroll
            for (int dsb = 0; dsb < 4; ++dsb) {
                bf16x8 vf = *(const bf16x8*)(bA + 8192 + (dsb * 16 + lrow) * 128 +
                                             ((ks * 64 + lgrp * 16) ^ swl));
                oacc[dsb] = __builtin_amdgcn_mfma_f32_16x16x32_bf16(vf, pa, oacc[dsb], 0, 0, 0);
            }
        }
        __builtin_amdgcn_s_setprio(0);

        __syncthreads();
        char* tmp = bA; bA = bB; bB = tmp;
    }
#undef STAGE

    // final tile's deferred stores
#pragma unroll
    for (int ns = 0; ns < 4; ++ns)
        *(f32x4*)(arow + (NT - 1) * 64 + ns * 16) = pvs[ns];

    // epilogue: lane holds d = dsb*16 + lgrp*4 + rr for q = q0 + w*16 + lrow
    if (of32) {
        float* op = (float*)opart + (size_t)kz * T_SEQ * DMODEL +
                    (size_t)(q0 + w * 16 + lrow) * DMODEL + h * HDIM + lgrp * 4;
#pragma unroll
        for (int dsb = 0; dsb < 4; ++dsb)
            *(f32x4*)(op + dsb * 16) = oacc[dsb];
    } else {
        __bf16* op = (__bf16*)opart + (size_t)(q0 + w * 16 + lrow) * DMODEL + h * HDIM + lgrp * 4;
#pragma unroll
        for (int dsb = 0; dsb < 4; ++dsb) {
            bf16x4 ob;
            ob[0] = (__bf16)oacc[dsb][0]; ob[1] = (__bf16)oacc[dsb][1];
            ob[2] = (__bf16)oacc[dsb][2]; ob[3] = (__bf16)oacc[dsb][3];
            *(bf16x4*)(op + dsb * 16) = ob;
        }
    }
}

// ---------------------------------------------------------------------------
// Kernel 4: output projection.  out = (sum of O partials) @ Wo^T + bo
// ---------------------------------------------------------------------------
__global__ __launch_bounds__(256) void oproj_kernel(
    const void* __restrict__ opart, const float* __restrict__ Wo,
    const float* __restrict__ bo, float* __restrict__ out, int KSP2, int of32)
{
    __shared__ char lds[16384];
    char* Ab = lds;
    char* Bb = lds + 8192;

    const int m0 = blockIdx.x * 64;
    const int n0 = blockIdx.y * 64;
    const int tid  = threadIdx.x;
    const int w    = tid >> 6;
    const int lane = tid & 63;
    const int lrow = lane & 15;
    const int lgrp = lane >> 4;

    f32x4 acc[4] = {};
    const int r   = tid >> 2;
    const int c0e = (tid & 3) * 16;
    const int sw  = (r & 7) << 4;

    for (int kt = 0; kt < 8; ++kt) {
        const int k0 = kt * 64;
        if (of32) {
            const float* p0 = (const float*)opart + (size_t)(m0 + r) * DMODEL + k0 + c0e;
#pragma unroll
            for (int i = 0; i < 4; ++i) {
                f32x4 a4 = *(const f32x4*)(p0 + 4 * i);
                for (int s = 1; s < KSP2; ++s)
                    a4 = a4 + *(const f32x4*)(p0 + (size_t)s * T_SEQ * DMODEL + 4 * i);
                bf16x4 av;
                av[0] = (__bf16)a4[0]; av[1] = (__bf16)a4[1];
                av[2] = (__bf16)a4[2]; av[3] = (__bf16)a4[3];
                *(bf16x4*)(Ab + r * 128 + ((c0e * 2 + 8 * i) ^ sw)) = av;
            }
        } else {
            const __bf16* pa = (const __bf16*)opart + (size_t)(m0 + r) * DMODEL + k0 + c0e;
            bf16x8 a0 = *(const bf16x8*)pa;
            bf16x8 a1 = *(const bf16x8*)(pa + 8);
            *(bf16x8*)(Ab + r * 128 + ((c0e * 2) ^ sw)) = a0;
            *(bf16x8*)(Ab + r * 128 + ((c0e * 2 + 16) ^ sw)) = a1;
        }
        const float* gB = Wo + (size_t)(n0 + r) * DMODEL + k0 + c0e;
#pragma unroll
        for (int i = 0; i < 4; ++i) {
            float4 b4 = *(const float4*)(gB + 4 * i);
            bf16x4 bv4;
            bv4[0] = (__bf16)b4.x; bv4[1] = (__bf16)b4.y;
            bv4[2] = (__bf16)b4.z; bv4[3] = (__bf16)b4.w;
            *(bf16x4*)(Bb + r * 128 + ((c0e * 2 + 8 * i) ^ sw)) = bv4;
        }
        __syncthreads();
#pragma unroll
        for (int ks = 0; ks < 2; ++ks) {
            bf16x8 af = *(const bf16x8*)(Ab + (w * 16 + lrow) * 128 +
                                         ((ks * 64 + lgrp * 16) ^ ((lrow & 7) << 4)));
#pragma unroll
            for (int ns = 0; ns < 4; ++ns) {
                bf16x8 bf = *(const bf16x8*)(Bb + (ns * 16 + lrow) * 128 +
                                             ((ks * 64 + lgrp * 16) ^ ((lrow & 7) << 4)));
                acc[ns] = __builtin_amdgcn_mfma_f32_16x16x32_bf16(af, bf, acc[ns], 0, 0, 0);
            }
        }
        __syncthreads();
    }

#pragma unroll
    for (int ns = 0; ns < 4; ++ns) {
        float bcol = bo[n0 + ns * 16 + lrow];
#pragma unroll
        for (int rr = 0; rr < 4; ++rr) {
            int orow = m0 + w * 16 + lgrp * 4 + rr;
            out[(size_t)orow * DMODEL + n0 + ns * 16 + lrow] = acc[ns][rr] + bcol;
        }
    }
}

// ---------------------------------------------------------------------------
extern "C" void kernel_launch(void* const* d_in, const int* in_sizes, int n_in,
                              void* d_out, int out_size, void* d_ws, size_t ws_size,
                              hipStream_t stream) {
    const float* query = (const float*)d_in[0];
    const float* key   = (const float*)d_in[1];
    const float* value = (const float*)d_in[2];
    const int*   mask  = (const int*)d_in[3];
    const float* Wq = (const float*)d_in[4];
    const float* bq = (const float*)d_in[5];
    const float* Wk = (const float*)d_in[6];
    const float* bk = (const float*)d_in[7];
    const float* Wv = (const float*)d_in[8];
    const float* bv = (const float*)d_in[9];
    const float* Wo = (const float*)d_in[10];
    const float* bo = (const float*)d_in[11];

    float* out  = (float*)d_out;
    float* attn = out + (size_t)T_SEQ * DMODEL;

    char* ws = (char*)d_ws;
    __bf16* qo     = (__bf16*)(ws);
    __bf16* ko     = (__bf16*)(ws + (4u << 20));
    __bf16* vt     = (__bf16*)(ws + (8u << 20));
    float*  l_part = (float*)(ws + (12u << 20));                  // 512 KB
    void*   opart  = (void*)(ws + (12u << 20) + (1u << 19));
    const size_t obase = (12u << 20) + (1u << 19);

    int KSP2, of32;
    const size_t oslice = (size_t)T_SEQ * DMODEL * 4;             // 8 MB f32
    if (ws_size >= obase + 2 * oslice)      { KSP2 = 2; of32 = 1; }
    else if (ws_size >= obase + oslice)     { KSP2 = 1; of32 = 1; }
    else                                    { KSP2 = 1; of32 = 0; }

    qkv_kernel<<<dim3(64, 8, 3), 256, 0, stream>>>(query, key, value,
                                                   Wq, bq, Wk, bk, Wv, bv, qo, ko, vt);
    attn_stats<<<dim3(32 * NH * KS1), 256, 0, stream>>>(qo, ko, mask, l_part);
    attn_main<<<dim3(64 * NH * KSP2), 256, 0, stream>>>(qo, ko, vt, mask, l_part,
                                                        attn, opart, KSP2, of32);
    oproj_kernel<<<dim3(64, 8), 256, 0, stream>>>(opart, Wo, bo, out, KSP2, of32);
}